// Round 3
// baseline (102.863 us; speedup 1.0000x reference)
//
#include <hip/hip_runtime.h>
#include <hip/hip_bf16.h>
#include <hip/hip_cooperative_groups.h>
#include <stdint.h>

namespace cg = cooperative_groups;

// LinearAssignmentLossCE, O(E+T), fully fused into ONE cooperative kernel.
//
// For target t=(a,b):
//   K    = cntS[a] + cntD[b] - cntBoth(a,b)
//   lse  = log( sumS[a] + sumD[b] - sumBoth(a,b) )   (sums of exp(score))
//   idx  = min{ e : src[e]==a && dst[e]==b }
//   loss = exists ? (lse - score[idx]) / K : 0
// out = sum_t loss / T
//
// exp(score) unscaled is exact-safe here (scores ~ N(0,1); round-1/2 absmax
// was 0.0 vs the np reference).
//
// Phases (grid.sync between): init ws -> edge aggregation (atomics + hash
// CAS) -> target lookup (1 target/thread over 32k threads) -> final write.
// Round-2 lesson: the single-block target pass was a 45us latency wall
// (one CU's miss queue serving 40k scattered loads); spreading it over
// 128 CUs makes it ~2us.

#define HLOG 17
#define HSZ  (1u << HLOG)   // 131072 hash slots, load factor ~0.5
#define NCAP 16384          // supports num_nodes up to 16384 (N=10000)
#define NBLK 128
#define TPB  256
#define NTH  (NBLK * TPB)   // 32768 threads

// ws layout (32-bit words):
//   [0,H)          keys (u32, 0xFFFFFFFF = empty)
//   [H,2H)         hsum (f32)
//   [2H,3H)        hcnt (u32)
//   [3H,4H)        hmin (i32, INT_MAX init)
//   [4H, +NCAP)    sumS (f32)
//   [+NCAP)        sumD (f32)
//   [+NCAP)        cntS (u32)
//   [+NCAP)        cntD (u32)
//   [1 word]       acc  (f32) global loss accumulator
#define WORDS_TABLES (4 * HSZ + 4 * NCAP)
#define WORDS_ALL    (WORDS_TABLES + 1)

__device__ __forceinline__ uint32_t hmix(uint32_t k) {
    k *= 2654435761u;
    k ^= k >> 15;
    return k;
}

__global__ __launch_bounds__(TPB) void la_fused(
    const int* __restrict__ src, const int* __restrict__ dst,
    const float* __restrict__ score,
    const int* __restrict__ tsrc, const int* __restrict__ tdst,
    const int* __restrict__ pN,
    uint32_t* __restrict__ ws, float* __restrict__ out, int E, int T)
{
    cg::grid_group grid = cg::this_grid();
    const int gtid = blockIdx.x * TPB + threadIdx.x;

    uint32_t* keys = ws;
    float*    hsum = (float*)(ws + HSZ);
    uint32_t* hcnt = ws + 2 * HSZ;
    int*      hmin = (int*)(ws + 3 * HSZ);
    float*    sumS = (float*)(ws + 4 * HSZ);
    float*    sumD = sumS + NCAP;
    uint32_t* cntS = (uint32_t*)(sumD + NCAP);
    uint32_t* cntD = cntS + NCAP;
    float*    acc  = (float*)(ws + WORDS_TABLES);

    const int N = *pN;

    // ---- Phase 0: init tables -------------------------------------------
    for (int i = gtid; i < (int)WORDS_ALL; i += NTH) {
        uint32_t v;
        if (i < (int)HSZ)            v = 0xFFFFFFFFu;  // keys empty
        else if (i < (int)(3 * HSZ)) v = 0u;           // hsum, hcnt
        else if (i < (int)(4 * HSZ)) v = 0x7FFFFFFFu;  // hmin = INT_MAX
        else                         v = 0u;           // node aggs + acc
        ws[i] = v;
    }
    grid.sync();

    // ---- Phase 1: edge aggregation --------------------------------------
    for (int e = gtid; e < E; e += NTH) {
        const int s = src[e], d = dst[e];
        const float ev = __expf(score[e]);

        atomicAdd(&sumS[s], ev);
        atomicAdd(&sumD[d], ev);
        atomicAdd(&cntS[s], 1u);
        atomicAdd(&cntD[d], 1u);

        const uint32_t key = (uint32_t)s * (uint32_t)N + (uint32_t)d;
        uint32_t h = hmix(key) & (HSZ - 1);
        while (true) {
            const uint32_t prev = atomicCAS(&keys[h], 0xFFFFFFFFu, key);
            if (prev == 0xFFFFFFFFu || prev == key) break;
            h = (h + 1) & (HSZ - 1);
        }
        atomicAdd(&hsum[h], ev);
        atomicAdd(&hcnt[h], 1u);
        atomicMin(&hmin[h], e);
    }
    grid.sync();

    // ---- Phase 2: target lookups (1 target/thread) ----------------------
    float local = 0.0f;
    for (int t = gtid; t < T; t += NTH) {
        const int a = tsrc[t], b = tdst[t];
        const uint32_t key = (uint32_t)a * (uint32_t)N + (uint32_t)b;
        uint32_t h = hmix(key) & (HSZ - 1);
        int slot = -1;
        while (true) {
            const uint32_t k2 = keys[h];
            if (k2 == key) { slot = (int)h; break; }
            if (k2 == 0xFFFFFFFFu) break;  // target edge absent
            h = (h + 1) & (HSZ - 1);
        }
        if (slot >= 0) {
            const float S = sumS[a] + sumD[b] - hsum[slot];
            const float K = (float)(int)(cntS[a] + cntD[b] - hcnt[slot]);
            local += (logf(S) - score[hmin[slot]]) / K;
        }
    }
    // wave reduce, one atomic per wave (512 total; order jitter ~1e-6)
    for (int off = 32; off > 0; off >>= 1) local += __shfl_down(local, off);
    if ((threadIdx.x & 63) == 0 && local != 0.0f) atomicAdd(acc, local);
    grid.sync();

    // ---- Phase 3: final write -------------------------------------------
    if (gtid == 0) out[0] = acc[0] / (float)T;
}

// ---------------------------------------------------------------------------
// Fallback (ws too small for tables): round-1 brute force, needs T*4 bytes.
// ---------------------------------------------------------------------------
#define NT   8
#define BLK  256

__global__ __launch_bounds__(BLK) void la_loss_main(
    const int* __restrict__ src, const int* __restrict__ dst,
    const float* __restrict__ score,
    const int* __restrict__ tsrc, const int* __restrict__ tdst,
    float* __restrict__ partial, int E, int T)
{
    const int tid   = threadIdx.x;
    const int tbase = blockIdx.x * NT;
    if (tbase >= T) return;

    int ts[NT], td[NT];
#pragma unroll
    for (int j = 0; j < NT; ++j) {
        int tj = tbase + j; if (tj > T - 1) tj = T - 1;
        ts[j] = tsrc[tj];
        td[j] = tdst[tj];
    }

    float S[NT]; float Kc[NT]; int idx[NT];
#pragma unroll
    for (int j = 0; j < NT; ++j) { S[j] = 0.0f; Kc[j] = 0.0f; idx[j] = 0x7fffffff; }

    for (int it = tid * 4; it < E; it += BLK * 4) {
        const int4   vs = *reinterpret_cast<const int4*>(src + it);
        const int4   vd = *reinterpret_cast<const int4*>(dst + it);
        const float4 sc = *reinterpret_cast<const float4*>(score + it);
        const int   es[4] = { vs.x, vs.y, vs.z, vs.w };
        const int   ed[4] = { vd.x, vd.y, vd.z, vd.w };
        const float ev[4] = { __expf(sc.x), __expf(sc.y), __expf(sc.z), __expf(sc.w) };
#pragma unroll
        for (int j = 0; j < NT; ++j) {
#pragma unroll
            for (int k = 0; k < 4; ++k) {
                const bool ms = (es[k] == ts[j]);
                const bool md = (ed[k] == td[j]);
                const bool m  = ms | md;
                S[j]  += m ? ev[k] : 0.0f;
                Kc[j] += m ? 1.0f  : 0.0f;
                idx[j] = (ms & md) ? min(idx[j], it + k) : idx[j];
            }
        }
    }

#pragma unroll
    for (int j = 0; j < NT; ++j) {
        for (int off = 32; off > 0; off >>= 1) {
            S[j]  += __shfl_down(S[j],  off);
            Kc[j] += __shfl_down(Kc[j], off);
            idx[j] = min(idx[j], __shfl_down(idx[j], off));
        }
    }

    __shared__ float sS[4][NT];
    __shared__ float sK[4][NT];
    __shared__ int   sI[4][NT];
    const int wave = tid >> 6;
    const int lane = tid & 63;
    if (lane == 0) {
#pragma unroll
        for (int j = 0; j < NT; ++j) { sS[wave][j] = S[j]; sK[wave][j] = Kc[j]; sI[wave][j] = idx[j]; }
    }
    __syncthreads();

    if (tid < NT && (tbase + tid) < T) {
        float Ssum = 0.0f, Ksum = 0.0f;
        int im = 0x7fffffff;
#pragma unroll
        for (int w = 0; w < 4; ++w) {
            Ssum += sS[w][tid]; Ksum += sK[w][tid]; im = min(im, sI[w][tid]);
        }
        float loss = 0.0f;
        if (im != 0x7fffffff) loss = (logf(Ssum) - score[im]) / Ksum;
        partial[tbase + tid] = loss;
    }
}

__global__ __launch_bounds__(256) void la_loss_reduce(
    const float* __restrict__ partial, float* __restrict__ out, int T)
{
    float s = 0.0f;
    for (int i = threadIdx.x; i < T; i += 256) s += partial[i];
    for (int off = 32; off > 0; off >>= 1) s += __shfl_down(s, off);
    __shared__ float acc[4];
    if ((threadIdx.x & 63) == 0) acc[threadIdx.x >> 6] = s;
    __syncthreads();
    if (threadIdx.x == 0) out[0] = (acc[0] + acc[1] + acc[2] + acc[3]) / (float)T;
}

// ---------------------------------------------------------------------------

extern "C" void kernel_launch(void* const* d_in, const int* in_sizes, int n_in,
                              void* d_out, int out_size, void* d_ws, size_t ws_size,
                              hipStream_t stream) {
    const int*   edge_index = (const int*)d_in[0];   // (2, E) int32
    const float* score      = (const float*)d_in[1]; // (E,)   f32
    const int*   target     = (const int*)d_in[2];   // (2, T) int32
    const int*   pN         = (const int*)d_in[3];   // num_nodes (device scalar)

    const int E = in_sizes[0] / 2;
    const int T = in_sizes[2] / 2;

    const int* src  = edge_index;
    const int* dst  = edge_index + E;
    const int* tsrc = target;
    const int* tdst = target + T;

    const size_t need = (size_t)WORDS_ALL * 4;
    if (ws_size >= need) {
        uint32_t* ws   = (uint32_t*)d_ws;
        float*    outp = (float*)d_out;
        void* args[] = {
            (void*)&src, (void*)&dst, (void*)&score,
            (void*)&tsrc, (void*)&tdst, (void*)&pN,
            (void*)&ws, (void*)&outp, (void*)&E, (void*)&T
        };
        hipLaunchCooperativeKernel((const void*)la_fused, dim3(NBLK), dim3(TPB),
                                   args, 0, stream);
    } else {
        float* partial = (float*)d_ws;  // T floats
        la_loss_main<<<(T + NT - 1) / NT, BLK, 0, stream>>>(src, dst, score,
                                                            tsrc, tdst, partial, E, T);
        la_loss_reduce<<<1, 256, 0, stream>>>(partial, (float*)d_out, T);
    }
}

// Round 4
// 36.426 us; speedup vs baseline: 2.8239x; 2.8239x over previous
//
#include <hip/hip_runtime.h>
#include <hip/hip_bf16.h>
#include <stdint.h>

// LinearAssignmentLossCE, O(E+T), atomic-minimized, bit-deterministic.
//
// For target t=(a,b):
//   K    = cntS[a] + cntD[b] - cntBoth(a,b)
//   lse  = log( sumS[a] + sumD[b] - sumBoth(a,b) )   (sums of exp(score))
//   idx  = min{ e : src[e]==a && dst[e]==b }
//   loss = exists ? (lse - score[idx]) / K : 0
// out = sum_t loss / T
//
// Round-3 lesson: device-scope atomics on gfx950 are write-through fabric
// transactions (WRITE_SIZE was 22.6MB for a 2.3MB ws); the old scheme's
// ~525K atomics/call were the wall. This version:
//   - hashes only the T target keys (inserted up front); the edge pass
//     probes READ-ONLY and only ~T matching edges do slot atomics;
//   - packs (count<<40 | fixed_point_sum) into ONE u64 atomicAdd per node
//     table (scale 2^22; exp(score) <~ 120, degree <~ 30 -> fix < 2^40/20);
//   - integer sums make inclusion-exclusion EXACT and order-independent,
//     so results are bit-identical across replays (no float atomics).
// Total atomics: ~140K vs ~525K.
//
// Visibility across kernels relies on stream-ordered kernel boundaries
// (HSA release/acquire) -- no cooperative launch, no grid.sync.

#define HLOG 13
#define HSZ  (1u << HLOG)        // 8192 slots for <=4096 target keys
#define NCAP 16384               // supports node ids < 16384 (N=10000)
#define EMPTY64 0xFFFFFFFFFFFFFFFFull
#define M40     ((1ull << 40) - 1)
#define CNT1    (1ull << 40)
#define FSCALE      4194304.0f   // 2^22
#define INV_FSCALE  (1.0f / 4194304.0f)

typedef unsigned long long u64;
typedef unsigned int u32;

__device__ __forceinline__ u32 hash64(u64 k) {
    return (u32)((k * 0x9E3779B97F4A7C15ull) >> (64 - HLOG));  // Fibonacci
}

// ---- K1: insert target keys (CAS-claim; duplicates share a slot) ---------
__global__ __launch_bounds__(256) void la_insert(
    const int* __restrict__ tsrc, const int* __restrict__ tdst,
    u64* __restrict__ hkey, int T)
{
    const int t = blockIdx.x * 256 + threadIdx.x;
    if (t >= T) return;
    const u64 key = ((u64)(u32)tsrc[t] << 32) | (u32)tdst[t];
    u32 h = hash64(key);
    while (true) {
        const u64 prev = atomicCAS(&hkey[h], EMPTY64, key);
        if (prev == EMPTY64 || prev == key) break;
        h = (h + 1) & (HSZ - 1);
    }
}

// ---- K2: edge aggregation -------------------------------------------------
__global__ __launch_bounds__(256) void la_edges(
    const int* __restrict__ src, const int* __restrict__ dst,
    const float* __restrict__ score,
    const u64* __restrict__ hkey, u64* __restrict__ hpack,
    u32* __restrict__ hmin,
    u64* __restrict__ nodeS, u64* __restrict__ nodeD, int E)
{
    const int e = blockIdx.x * 256 + threadIdx.x;
    if (e >= E) return;
    const int s = src[e], d = dst[e];
    const float ev = __expf(score[e]);
    const u64 add = (u64)(ev * FSCALE + 0.5f) + CNT1;  // (cnt=1)<<40 | fix

    atomicAdd(&nodeS[s], add);
    atomicAdd(&nodeD[d], add);

    // read-only probe of the target-key hash; ~94% of edges miss and do
    // nothing; only exact target-edge matches pay slot atomics.
    const u64 key = ((u64)(u32)s << 32) | (u32)d;
    u32 h = hash64(key);
    while (true) {
        const u64 k2 = hkey[h];
        if (k2 == EMPTY64) break;        // not a target edge
        if (k2 == key) {
            atomicAdd(&hpack[h], add);
            atomicMin(&hmin[h], (u32)e);
            break;
        }
        h = (h + 1) & (HSZ - 1);
    }
}

// ---- K3: per-target lookup + per-block partial (deterministic) -----------
__global__ __launch_bounds__(64) void la_targets(
    const int* __restrict__ tsrc, const int* __restrict__ tdst,
    const float* __restrict__ score,
    const u64* __restrict__ hkey, const u64* __restrict__ hpack,
    const u32* __restrict__ hmin,
    const u64* __restrict__ nodeS, const u64* __restrict__ nodeD,
    float* __restrict__ partial, int T)
{
    const int t = blockIdx.x * 64 + threadIdx.x;
    float local = 0.0f;
    if (t < T) {
        const int a = tsrc[t], b = tdst[t];
        const u64 key = ((u64)(u32)a << 32) | (u32)b;
        u32 h = hash64(key);
        int slot = -1;
        while (true) {
            const u64 k2 = hkey[h];
            if (k2 == key) { slot = (int)h; break; }
            if (k2 == EMPTY64) break;    // defensive; key was inserted in K1
            h = (h + 1) & (HSZ - 1);
        }
        if (slot >= 0) {
            const u64 pk = hpack[slot];
            const u64 cb = pk >> 40;
            if (cb > 0) {                // target edge exists among edges
                const u64 pa = nodeS[a], pb = nodeD[b];
                const u64 Sfix = (pa & M40) + (pb & M40) - (pk & M40); // exact
                const u64 Kc   = (pa >> 40) + (pb >> 40) - cb;
                const float S  = (float)Sfix * INV_FSCALE;
                local = (logf(S) - score[hmin[slot]]) / (float)Kc;
            }
        }
    }
    // full-wave butterfly (blockDim = 64 = one wave, all lanes active)
    for (int off = 32; off > 0; off >>= 1) local += __shfl_down(local, off);
    if (threadIdx.x == 0) partial[blockIdx.x] = local;
}

// ---- K4: final fixed-order reduce ----------------------------------------
__global__ __launch_bounds__(64) void la_final(
    const float* __restrict__ partial, float* __restrict__ out, int nb, int T)
{
    float s = 0.0f;
    for (int i = threadIdx.x; i < nb; i += 64) s += partial[i];
    for (int off = 32; off > 0; off >>= 1) s += __shfl_down(s, off);
    if (threadIdx.x == 0) out[0] = s / (float)T;
}

// ---------------------------------------------------------------------------
// Fallback (ws too small): round-1 brute force, needs T*4 bytes of ws.
// ---------------------------------------------------------------------------
#define NT   8
#define BLK  256

__global__ __launch_bounds__(BLK) void la_loss_main(
    const int* __restrict__ src, const int* __restrict__ dst,
    const float* __restrict__ score,
    const int* __restrict__ tsrc, const int* __restrict__ tdst,
    float* __restrict__ partial, int E, int T)
{
    const int tid   = threadIdx.x;
    const int tbase = blockIdx.x * NT;
    if (tbase >= T) return;

    int ts[NT], td[NT];
#pragma unroll
    for (int j = 0; j < NT; ++j) {
        int tj = tbase + j; if (tj > T - 1) tj = T - 1;
        ts[j] = tsrc[tj];
        td[j] = tdst[tj];
    }

    float S[NT]; float Kc[NT]; int idx[NT];
#pragma unroll
    for (int j = 0; j < NT; ++j) { S[j] = 0.0f; Kc[j] = 0.0f; idx[j] = 0x7fffffff; }

    for (int it = tid * 4; it < E; it += BLK * 4) {
        const int4   vs = *reinterpret_cast<const int4*>(src + it);
        const int4   vd = *reinterpret_cast<const int4*>(dst + it);
        const float4 sc = *reinterpret_cast<const float4*>(score + it);
        const int   es[4] = { vs.x, vs.y, vs.z, vs.w };
        const int   ed[4] = { vd.x, vd.y, vd.z, vd.w };
        const float ev[4] = { __expf(sc.x), __expf(sc.y), __expf(sc.z), __expf(sc.w) };
#pragma unroll
        for (int j = 0; j < NT; ++j) {
#pragma unroll
            for (int k = 0; k < 4; ++k) {
                const bool ms = (es[k] == ts[j]);
                const bool md = (ed[k] == td[j]);
                const bool m  = ms | md;
                S[j]  += m ? ev[k] : 0.0f;
                Kc[j] += m ? 1.0f  : 0.0f;
                idx[j] = (ms & md) ? min(idx[j], it + k) : idx[j];
            }
        }
    }

#pragma unroll
    for (int j = 0; j < NT; ++j) {
        for (int off = 32; off > 0; off >>= 1) {
            S[j]  += __shfl_down(S[j],  off);
            Kc[j] += __shfl_down(Kc[j], off);
            idx[j] = min(idx[j], __shfl_down(idx[j], off));
        }
    }

    __shared__ float sS[4][NT];
    __shared__ float sK[4][NT];
    __shared__ int   sI[4][NT];
    const int wave = tid >> 6;
    const int lane = tid & 63;
    if (lane == 0) {
#pragma unroll
        for (int j = 0; j < NT; ++j) { sS[wave][j] = S[j]; sK[wave][j] = Kc[j]; sI[wave][j] = idx[j]; }
    }
    __syncthreads();

    if (tid < NT && (tbase + tid) < T) {
        float Ssum = 0.0f, Ksum = 0.0f;
        int im = 0x7fffffff;
#pragma unroll
        for (int w = 0; w < 4; ++w) {
            Ssum += sS[w][tid]; Ksum += sK[w][tid]; im = min(im, sI[w][tid]);
        }
        float loss = 0.0f;
        if (im != 0x7fffffff) loss = (logf(Ssum) - score[im]) / Ksum;
        partial[tbase + tid] = loss;
    }
}

__global__ __launch_bounds__(256) void la_loss_reduce(
    const float* __restrict__ partial, float* __restrict__ out, int T)
{
    float s = 0.0f;
    for (int i = threadIdx.x; i < T; i += 256) s += partial[i];
    for (int off = 32; off > 0; off >>= 1) s += __shfl_down(s, off);
    __shared__ float acc[4];
    if ((threadIdx.x & 63) == 0) acc[threadIdx.x >> 6] = s;
    __syncthreads();
    if (threadIdx.x == 0) out[0] = (acc[0] + acc[1] + acc[2] + acc[3]) / (float)T;
}

// ---------------------------------------------------------------------------

extern "C" void kernel_launch(void* const* d_in, const int* in_sizes, int n_in,
                              void* d_out, int out_size, void* d_ws, size_t ws_size,
                              hipStream_t stream) {
    const int*   edge_index = (const int*)d_in[0];   // (2, E) int32
    const float* score      = (const float*)d_in[1]; // (E,)   f32
    const int*   target     = (const int*)d_in[2];   // (2, T) int32
    // d_in[3] = num_nodes (device scalar) -- unused: keys are (src<<32|dst)

    const int E = in_sizes[0] / 2;
    const int T = in_sizes[2] / 2;

    const int* src  = edge_index;
    const int* dst  = edge_index + E;
    const int* tsrc = target;
    const int* tdst = target + T;

    // ws layout (all 8B-aligned):
    //   hkey  u64[HSZ]   64KB   memset 0xFF (EMPTY)
    //   hmin  u32[HSZ]   32KB   memset 0xFF (UINT_MAX)
    //   hpack u64[HSZ]   64KB   memset 0
    //   nodeS u64[NCAP] 128KB   memset 0
    //   nodeD u64[NCAP] 128KB   memset 0
    //   partial f32[nb3]
    const size_t HKEY_B  = (size_t)HSZ * 8;
    const size_t HMIN_B  = (size_t)HSZ * 4;
    const size_t HPACK_B = (size_t)HSZ * 8;
    const size_t NODE_B  = (size_t)NCAP * 8;
    const int    nb3     = (T + 63) / 64;
    const size_t need = HKEY_B + HMIN_B + HPACK_B + 2 * NODE_B + (size_t)nb3 * 4;

    if (ws_size >= need) {
        uint8_t* p = (uint8_t*)d_ws;
        u64* hkey    = (u64*)p;                 p += HKEY_B;
        u32* hmin    = (u32*)p;                 p += HMIN_B;
        u64* hpack   = (u64*)p;                 p += HPACK_B;
        u64* nodeS   = (u64*)p;                 p += NODE_B;
        u64* nodeD   = (u64*)p;                 p += NODE_B;
        float* partial = (float*)p;

        hipMemsetAsync(hkey,  0xFF, HKEY_B + HMIN_B, stream);          // keys+min
        hipMemsetAsync(hpack, 0x00, HPACK_B + 2 * NODE_B, stream);     // sums

        la_insert<<<(T + 255) / 256, 256, 0, stream>>>(tsrc, tdst, hkey, T);
        la_edges<<<(E + 255) / 256, 256, 0, stream>>>(src, dst, score, hkey,
                                                      hpack, hmin, nodeS, nodeD, E);
        la_targets<<<nb3, 64, 0, stream>>>(tsrc, tdst, score, hkey, hpack, hmin,
                                           nodeS, nodeD, partial, T);
        la_final<<<1, 64, 0, stream>>>(partial, (float*)d_out, nb3, T);
    } else {
        float* partial = (float*)d_ws;  // T floats
        la_loss_main<<<(T + NT - 1) / NT, BLK, 0, stream>>>(src, dst, score,
                                                            tsrc, tdst, partial, E, T);
        la_loss_reduce<<<1, 256, 0, stream>>>(partial, (float*)d_out, T);
    }
}

// Round 5
// 33.446 us; speedup vs baseline: 3.0755x; 1.0891x over previous
//
#include <hip/hip_runtime.h>
#include <hip/hip_bf16.h>
#include <stdint.h>

// LinearAssignmentLossCE, O(E+T), 4 dispatches, bit-deterministic.
//
// For target t=(a,b):
//   K    = cntS[a] + cntD[b] - cntBoth(a,b)
//   lse  = log( sumS[a] + sumD[b] - sumBoth(a,b) )   (sums of exp(score))
//   idx  = min{ e : src[e]==a && dst[e]==b }
//   loss = exists ? (lse - score[idx]) / K : 0
// out = sum_t loss / T
//
// Evolution: R1 brute force 113us (VALU wall) -> R2 hash join 88us (1-block
// target pass = latency wall) -> R3 cooperative fusion 103us (525K device
// atomics write through fabric: 22.6MB WRITE_SIZE) -> R4 target-keyed hash +
// packed u64 fixed-point atomics 36us (dispatch-count bound).
// R5: 6 dispatches -> 4 (init kernel replaces 2 memsets; last-block finish
// replaces the final-reduce kernel) and node-bitmap filtering cuts atomics
// ~140K -> ~60K (only nodes read by some target get aggregated; only edges
// whose (src,dst) both hit target-node bitmaps probe the hash).
//
// Fixed-point packing: (cnt<<40) | round(exp(score)*2^22) in one u64
// atomicAdd -> integer inclusion-exclusion is exact and order-independent,
// so output is bit-identical across replays. exp(score) <= ~120 for N(0,1)
// scores; degree <~ 40 -> fix sum < 2^33 << 2^40.

#define HLOG 13
#define HSZ  (1u << HLOG)        // 8192 slots for <=4096 target keys
#define NCAP 16384               // node ids < 16384 (N=10000)
#define NBW  (NCAP / 32)         // bitmap words
#define EMPTY64 0xFFFFFFFFFFFFFFFFull
#define M40     ((1ull << 40) - 1)
#define CNT1    (1ull << 40)
#define FSCALE      4194304.0f   // 2^22
#define INV_FSCALE  (1.0f / 4194304.0f)

typedef unsigned long long u64;
typedef unsigned int u32;

__device__ __forceinline__ u32 hash64(u64 k) {
    return (u32)((k * 0x9E3779B97F4A7C15ull) >> (64 - HLOG));  // Fibonacci
}

// ws layout (u64-aligned), two contiguous init spans:
//   FF span : hkey u64[HSZ] | hmin u32[HSZ]                  (96 KB, 0xFF)
//   00 span : hpack u64[HSZ] | nodeS u64[NCAP] | nodeD u64[NCAP]
//             | sbit u32[NBW] | dbit u32[NBW] | done u32 | pad u32  (~324 KB, 0)
//   partial f32[nb] (written every call before being read; no init)
#define FF_BYTES   ((size_t)HSZ * 8 + (size_t)HSZ * 4)
#define Z_BYTES    ((size_t)HSZ * 8 + 2 * (size_t)NCAP * 8 + 2 * (size_t)NBW * 4 + 8)

// ---- K0: init tables ------------------------------------------------------
__global__ __launch_bounds__(256) void la_init(u64* __restrict__ p,
                                               int n_ff, int n_tot)
{
    int i = blockIdx.x * 256 + threadIdx.x;
    const int stride = gridDim.x * 256;
    for (; i < n_tot; i += stride)
        p[i] = (i < n_ff) ? EMPTY64 : 0ull;
}

// ---- K1: insert target keys + set node bitmaps ---------------------------
__global__ __launch_bounds__(256) void la_insert(
    const int* __restrict__ tsrc, const int* __restrict__ tdst,
    u64* __restrict__ hkey, u32* __restrict__ sbit, u32* __restrict__ dbit,
    int T)
{
    const int t = blockIdx.x * 256 + threadIdx.x;
    if (t >= T) return;
    const u32 a = (u32)tsrc[t], b = (u32)tdst[t];
    if (a < NCAP) atomicOr(&sbit[a >> 5], 1u << (a & 31));
    if (b < NCAP) atomicOr(&dbit[b >> 5], 1u << (b & 31));
    const u64 key = ((u64)a << 32) | b;
    u32 h = hash64(key);
    while (true) {
        const u64 prev = atomicCAS(&hkey[h], EMPTY64, key);
        if (prev == EMPTY64 || prev == key) break;
        h = (h + 1) & (HSZ - 1);
    }
}

// ---- K2: edge aggregation (bitmap-filtered) ------------------------------
__global__ __launch_bounds__(256) void la_edges(
    const int* __restrict__ src, const int* __restrict__ dst,
    const float* __restrict__ score,
    const u64* __restrict__ hkey, u64* __restrict__ hpack,
    u32* __restrict__ hmin,
    u64* __restrict__ nodeS, u64* __restrict__ nodeD,
    const u32* __restrict__ sbit, const u32* __restrict__ dbit, int E)
{
    const int e = blockIdx.x * 256 + threadIdx.x;
    if (e >= E) return;
    const u32 s = (u32)src[e], d = (u32)dst[e];
    if (s >= NCAP || d >= NCAP) return;  // defensive (N=10000 < NCAP)

    const bool hs = (sbit[s >> 5] >> (s & 31)) & 1u;
    const bool hd = (dbit[d >> 5] >> (d & 31)) & 1u;
    if (!hs && !hd) return;              // node never read by any target

    const float ev = __expf(score[e]);
    const u64 add = (u64)(ev * FSCALE + 0.5f) + CNT1;  // (cnt=1)<<40 | fix

    if (hs) atomicAdd(&nodeS[s], add);
    if (hd) atomicAdd(&nodeD[d], add);

    if (hs && hd) {                      // only then can (s,d) be a target key
        const u64 key = ((u64)s << 32) | d;
        u32 h = hash64(key);
        while (true) {
            const u64 k2 = hkey[h];
            if (k2 == EMPTY64) break;    // not a target edge
            if (k2 == key) {
                atomicAdd(&hpack[h], add);
                atomicMin(&hmin[h], (u32)e);
                break;
            }
            h = (h + 1) & (HSZ - 1);
        }
    }
}

// ---- K3: target lookup + last-block finish -------------------------------
__global__ __launch_bounds__(64) void la_targets(
    const int* __restrict__ tsrc, const int* __restrict__ tdst,
    const float* __restrict__ score,
    const u64* __restrict__ hkey, const u64* __restrict__ hpack,
    const u32* __restrict__ hmin,
    const u64* __restrict__ nodeS, const u64* __restrict__ nodeD,
    float* __restrict__ partial, u32* __restrict__ done,
    float* __restrict__ out, int T)
{
    const int nb = gridDim.x;
    const int t  = blockIdx.x * 64 + threadIdx.x;
    float local = 0.0f;
    if (t < T) {
        const u32 a = (u32)tsrc[t], b = (u32)tdst[t];
        const u64 key = ((u64)a << 32) | b;
        u32 h = hash64(key);
        int slot = -1;
        while (true) {
            const u64 k2 = hkey[h];
            if (k2 == key) { slot = (int)h; break; }
            if (k2 == EMPTY64) break;    // defensive; inserted in K1
            h = (h + 1) & (HSZ - 1);
        }
        if (slot >= 0) {
            const u64 pk = hpack[slot];
            const u64 cb = pk >> 40;
            if (cb > 0) {                // target edge exists
                const u64 pa = nodeS[a], pb = nodeD[b];
                const u64 Sfix = (pa & M40) + (pb & M40) - (pk & M40); // exact
                const u64 Kc   = (pa >> 40) + (pb >> 40) - cb;
                const float S  = (float)Sfix * INV_FSCALE;
                local = (logf(S) - score[hmin[slot]]) / (float)Kc;
            }
        }
    }
    // full-wave butterfly (blockDim == 64 == one wave)
    for (int off = 32; off > 0; off >>= 1) local += __shfl_down(local, off);

    __shared__ int lastFlag;
    if (threadIdx.x == 0) {
        __hip_atomic_store(&partial[blockIdx.x], local, __ATOMIC_RELEASE,
                           __HIP_MEMORY_SCOPE_AGENT);
        const u32 prev = __hip_atomic_fetch_add(done, 1u, __ATOMIC_ACQ_REL,
                                                __HIP_MEMORY_SCOPE_AGENT);
        lastFlag = (prev == (u32)(nb - 1));
    }
    __syncthreads();  // extends thread-0's device-acquire block-wide

    if (lastFlag) {
        // fixed-order reduce of nb partials (nb <= 64 here; strided if more)
        float s = 0.0f;
        for (int i = threadIdx.x; i < nb; i += 64)
            s += __hip_atomic_load(&partial[i], __ATOMIC_RELAXED,
                                   __HIP_MEMORY_SCOPE_AGENT);
        for (int off = 32; off > 0; off >>= 1) s += __shfl_down(s, off);
        if (threadIdx.x == 0) out[0] = s / (float)T;
    }
}

// ---------------------------------------------------------------------------
// Fallback (ws too small): round-1 brute force, needs T*4 bytes of ws.
// ---------------------------------------------------------------------------
#define NT   8
#define BLK  256

__global__ __launch_bounds__(BLK) void la_loss_main(
    const int* __restrict__ src, const int* __restrict__ dst,
    const float* __restrict__ score,
    const int* __restrict__ tsrc, const int* __restrict__ tdst,
    float* __restrict__ partial, int E, int T)
{
    const int tid   = threadIdx.x;
    const int tbase = blockIdx.x * NT;
    if (tbase >= T) return;

    int ts[NT], td[NT];
#pragma unroll
    for (int j = 0; j < NT; ++j) {
        int tj = tbase + j; if (tj > T - 1) tj = T - 1;
        ts[j] = tsrc[tj];
        td[j] = tdst[tj];
    }

    float S[NT]; float Kc[NT]; int idx[NT];
#pragma unroll
    for (int j = 0; j < NT; ++j) { S[j] = 0.0f; Kc[j] = 0.0f; idx[j] = 0x7fffffff; }

    for (int it = tid * 4; it < E; it += BLK * 4) {
        const int4   vs = *reinterpret_cast<const int4*>(src + it);
        const int4   vd = *reinterpret_cast<const int4*>(dst + it);
        const float4 sc = *reinterpret_cast<const float4*>(score + it);
        const int   es[4] = { vs.x, vs.y, vs.z, vs.w };
        const int   ed[4] = { vd.x, vd.y, vd.z, vd.w };
        const float ev[4] = { __expf(sc.x), __expf(sc.y), __expf(sc.z), __expf(sc.w) };
#pragma unroll
        for (int j = 0; j < NT; ++j) {
#pragma unroll
            for (int k = 0; k < 4; ++k) {
                const bool ms = (es[k] == ts[j]);
                const bool md = (ed[k] == td[j]);
                const bool m  = ms | md;
                S[j]  += m ? ev[k] : 0.0f;
                Kc[j] += m ? 1.0f  : 0.0f;
                idx[j] = (ms & md) ? min(idx[j], it + k) : idx[j];
            }
        }
    }

#pragma unroll
    for (int j = 0; j < NT; ++j) {
        for (int off = 32; off > 0; off >>= 1) {
            S[j]  += __shfl_down(S[j],  off);
            Kc[j] += __shfl_down(Kc[j], off);
            idx[j] = min(idx[j], __shfl_down(idx[j], off));
        }
    }

    __shared__ float sS[4][NT];
    __shared__ float sK[4][NT];
    __shared__ int   sI[4][NT];
    const int wave = tid >> 6;
    const int lane = tid & 63;
    if (lane == 0) {
#pragma unroll
        for (int j = 0; j < NT; ++j) { sS[wave][j] = S[j]; sK[wave][j] = Kc[j]; sI[wave][j] = idx[j]; }
    }
    __syncthreads();

    if (tid < NT && (tbase + tid) < T) {
        float Ssum = 0.0f, Ksum = 0.0f;
        int im = 0x7fffffff;
#pragma unroll
        for (int w = 0; w < 4; ++w) {
            Ssum += sS[w][tid]; Ksum += sK[w][tid]; im = min(im, sI[w][tid]);
        }
        float loss = 0.0f;
        if (im != 0x7fffffff) loss = (logf(Ssum) - score[im]) / Ksum;
        partial[tbase + tid] = loss;
    }
}

__global__ __launch_bounds__(256) void la_loss_reduce(
    const float* __restrict__ partial, float* __restrict__ out, int T)
{
    float s = 0.0f;
    for (int i = threadIdx.x; i < T; i += 256) s += partial[i];
    for (int off = 32; off > 0; off >>= 1) s += __shfl_down(s, off);
    __shared__ float acc[4];
    if ((threadIdx.x & 63) == 0) acc[threadIdx.x >> 6] = s;
    __syncthreads();
    if (threadIdx.x == 0) out[0] = (acc[0] + acc[1] + acc[2] + acc[3]) / (float)T;
}

// ---------------------------------------------------------------------------

extern "C" void kernel_launch(void* const* d_in, const int* in_sizes, int n_in,
                              void* d_out, int out_size, void* d_ws, size_t ws_size,
                              hipStream_t stream) {
    const int*   edge_index = (const int*)d_in[0];   // (2, E) int32
    const float* score      = (const float*)d_in[1]; // (E,)   f32
    const int*   target     = (const int*)d_in[2];   // (2, T) int32
    // d_in[3] = num_nodes (device scalar) -- unused: keys are (src<<32|dst)

    const int E = in_sizes[0] / 2;
    const int T = in_sizes[2] / 2;

    const int* src  = edge_index;
    const int* dst  = edge_index + E;
    const int* tsrc = target;
    const int* tdst = target + T;

    const int    nb   = (T + 63) / 64;
    const size_t need = FF_BYTES + Z_BYTES + (size_t)nb * 4;

    if (ws_size >= need) {
        uint8_t* p = (uint8_t*)d_ws;
        u64* hkey  = (u64*)p;                          p += (size_t)HSZ * 8;
        u32* hmin  = (u32*)p;                          p += (size_t)HSZ * 4;
        u64* hpack = (u64*)p;                          p += (size_t)HSZ * 8;
        u64* nodeS = (u64*)p;                          p += (size_t)NCAP * 8;
        u64* nodeD = (u64*)p;                          p += (size_t)NCAP * 8;
        u32* sbit  = (u32*)p;                          p += (size_t)NBW * 4;
        u32* dbit  = (u32*)p;                          p += (size_t)NBW * 4;
        u32* done  = (u32*)p;                          p += 8;  // + pad
        float* partial = (float*)p;

        const int n_ff  = (int)(FF_BYTES / 8);
        const int n_tot = (int)((FF_BYTES + Z_BYTES) / 8);

        la_init<<<64, 256, 0, stream>>>((u64*)d_ws, n_ff, n_tot);
        la_insert<<<(T + 255) / 256, 256, 0, stream>>>(tsrc, tdst, hkey,
                                                       sbit, dbit, T);
        la_edges<<<(E + 255) / 256, 256, 0, stream>>>(src, dst, score, hkey,
                                                      hpack, hmin, nodeS, nodeD,
                                                      sbit, dbit, E);
        la_targets<<<nb, 64, 0, stream>>>(tsrc, tdst, score, hkey, hpack, hmin,
                                          nodeS, nodeD, partial, done,
                                          (float*)d_out, T);
    } else {
        float* partial = (float*)d_ws;  // T floats
        la_loss_main<<<(T + NT - 1) / NT, BLK, 0, stream>>>(src, dst, score,
                                                            tsrc, tdst, partial, E, T);
        la_loss_reduce<<<1, 256, 0, stream>>>(partial, (float*)d_out, T);
    }
}